// Round 2
// baseline (852.959 us; speedup 1.0000x reference)
//
#include <hip/hip_runtime.h>
#include <float.h>
#include <math.h>

// Problem constants (reference: x shape (2,1024,32000) fp32, dim=-1, alpha=1.5)
#define D_DIM   32000
#define NT      256                         // 4 waves -> 8 blocks/CU (vs old 1024/2)
#define CHUNKS  (D_DIM / 4)                 // 8000 float4 chunks per row
#define KITER   ((CHUNKS + NT - 1) / NT)    // 32 strided iterations per thread
#define NWAVES  (NT / 64)                   // 4
#define CAPL    18                          // candidate slots per lane (Poisson(~2.7) tail-safe)
#define SEG     (64 * CAPL)                 // floats per wave segment (1152)

typedef float f32x4 __attribute__((ext_vector_type(4)));

__device__ __forceinline__ float waveReduceSum(float v) {
#pragma unroll
    for (int m = 32; m >= 1; m >>= 1) v += __shfl_xor(v, m, 64);
    return v;
}

__device__ __forceinline__ float waveReduceMax(float v) {
#pragma unroll
    for (int m = 32; m >= 1; m >>= 1) v = fmaxf(v, __shfl_xor(v, m, 64));
    return v;
}

// Bit-level finite scrub: maps NaN and +/-inf to -FLT_MAX. Integer-domain so
// -ffinite-math-only cannot fold it away.
__device__ __forceinline__ float scrub_finite(float v) {
    const unsigned u = __float_as_uint(v);
    if ((u & 0x7f800000u) == 0x7f800000u) return -FLT_MAX;
    return v;
}

__global__ __launch_bounds__(NT, 8)
void entmax_log_kernel(const float* __restrict__ x, float* __restrict__ out, int rows)
{
    const int row = blockIdx.x;
    if (row >= rows) return;
    const size_t base = (size_t)row * D_DIM;
    const float4* __restrict__ xr4 = reinterpret_cast<const float4*>(x + base);
    float* __restrict__ orow = out + base;

    // Per-wave candidate segments, layout [slot][lane] within each segment:
    // writes (lane-private columns) and strided scans are both bank-conflict-free.
    __shared__ __align__(16) float s_act[NWAVES * SEG];   // 18 KB
    __shared__ float s_red[NWAVES];
    __shared__ int   s_flag;

    const int lane = threadIdx.x & 63;
    const int wv   = threadIdx.x >> 6;
    float* __restrict__ seg = s_act + wv * SEG;

    // ---- init pads (so bisection can scan fixed CAPL slots; pads give t=0) ----
    {
        f32x4* sa4 = reinterpret_cast<f32x4*>(s_act);
#pragma unroll 2
        for (int i = threadIdx.x; i < (NWAVES * SEG) / 4; i += NT)
            sa4[i] = (f32x4){-FLT_MAX, -FLT_MAX, -FLT_MAX, -FLT_MAX};
        if (threadIdx.x == 0) s_flag = 0;
    }
    __syncthreads();

    // ---- pass 1: stream row; wave running max + single-pass candidate compaction ----
    // Admission threshold runM-1 with runM = wave running max (incl. current chunk).
    // runM <= final block max, so {z > runM-1} is a SUPERSET of the active set
    // {z > max-1}; extras contribute exactly 0 to every f(tau). Per-lane LDS
    // columns keep the order deterministic without any cross-lane traffic.
    float runM = -FLT_MAX;
    int n = 0;
    for (int k = 0; k < KITER; ++k) {
        const int c = threadIdx.x + k * NT;
        float z0, z1, z2, z3;
        if (c < CHUNKS) {
            const float4 v = xr4[c];
            z0 = v.x * 0.5f; z1 = v.y * 0.5f; z2 = v.z * 0.5f; z3 = v.w * 0.5f;
        } else {
            z0 = z1 = z2 = z3 = -FLT_MAX;
        }
        float cm = fmaxf(fmaxf(z0, z1), fmaxf(z2, z3));
        cm = waveReduceMax(cm);
        runM = fmaxf(runM, cm);
        const float thr = runM - 1.0f;
        if (z0 > thr) { if (n < CAPL) seg[n * 64 + lane] = z0; ++n; }
        if (z1 > thr) { if (n < CAPL) seg[n * 64 + lane] = z1; ++n; }
        if (z2 > thr) { if (n < CAPL) seg[n * 64 + lane] = z2; ++n; }
        if (z3 > thr) { if (n < CAPL) seg[n * 64 + lane] = z3; ++n; }
    }
    if (n > CAPL) s_flag = 1;   // column overflow -> streaming fallback

    if (lane == 0) s_red[wv] = runM;     // runM is wave-uniform after reduce
    __syncthreads();
    const float max_val = fmaxf(fmaxf(s_red[0], s_red[1]), fmaxf(s_red[2], s_red[3]));
    const int flag = s_flag;
    __syncthreads();                     // s_red is reused below

    float tau_lo = max_val - 1.0f;                          // gp(1) = 1
    const float tau_hi = max_val - 0.005590169943749474f;   // (1/32000)^0.5
    float tau_m, s_final;

    if (!flag) {
        // ---- 4-wave bisection: each wave scans its own padded segment ----
        // (spreads across all 4 SIMDs; with 8 blocks/CU one block's bisection
        // hides under the other blocks' memory phases)
        float fl = 0.0f;
#pragma unroll
        for (int k = 0; k < CAPL; ++k) {
            const float t = fmaxf(seg[k * 64 + lane] - tau_lo, 0.0f);
            fl = fmaf(t, t, fl);
        }
        fl = waveReduceSum(fl);
        if (lane == 0) s_red[wv] = fl;
        __syncthreads();
        const float f_lo = (s_red[0] + s_red[1] + s_red[2] + s_red[3]) - 1.0f;
        __syncthreads();

        float dm = tau_hi - tau_lo;
        tau_m = tau_lo;
        s_final = 1.0f;
        for (int it = 0; it < 100; ++it) {
            dm *= 0.5f;
            tau_m = tau_lo + dm;
            const bool fixed = (tau_m == tau_lo);   // uniform across block
            float a = 0.0f;
#pragma unroll
            for (int k = 0; k < CAPL; ++k) {
                const float t = fmaxf(seg[k * 64 + lane] - tau_m, 0.0f);
                a = fmaf(t, t, a);
            }
            a = waveReduceSum(a);
            if (lane == 0) s_red[wv] = a;
            __syncthreads();
            const float s = s_red[0] + s_red[1] + s_red[2] + s_red[3];
            __syncthreads();
            s_final = s;
            if ((s - 1.0f) * f_lo >= 0.0f) tau_lo = tau_m;
            if (fixed) break;
        }
    } else {
        // ---- fallback (statistically unreachable): stream row per iteration ----
        float acc = 0.0f;
        for (int k = 0; k < KITER; ++k) {
            const int c = threadIdx.x + k * NT;
            if (c < CHUNKS) {
                const float4 v = xr4[c];
                float t;
                t = fmaxf(v.x * 0.5f - tau_lo, 0.0f); acc = fmaf(t, t, acc);
                t = fmaxf(v.y * 0.5f - tau_lo, 0.0f); acc = fmaf(t, t, acc);
                t = fmaxf(v.z * 0.5f - tau_lo, 0.0f); acc = fmaf(t, t, acc);
                t = fmaxf(v.w * 0.5f - tau_lo, 0.0f); acc = fmaf(t, t, acc);
            }
        }
        acc = waveReduceSum(acc);
        if (lane == 0) s_red[wv] = acc;
        __syncthreads();
        const float f_lo = (s_red[0] + s_red[1] + s_red[2] + s_red[3]) - 1.0f;
        __syncthreads();

        float dm = tau_hi - tau_lo;
        tau_m = tau_lo;
        s_final = 1.0f;
        for (int it = 0; it < 100; ++it) {
            dm *= 0.5f;
            tau_m = tau_lo + dm;
            const bool fixed = (tau_m == tau_lo);
            float a = 0.0f;
            for (int k = 0; k < KITER; ++k) {
                const int c = threadIdx.x + k * NT;
                if (c < CHUNKS) {
                    const float4 v = xr4[c];
                    float t;
                    t = fmaxf(v.x * 0.5f - tau_m, 0.0f); a = fmaf(t, t, a);
                    t = fmaxf(v.y * 0.5f - tau_m, 0.0f); a = fmaf(t, t, a);
                    t = fmaxf(v.z * 0.5f - tau_m, 0.0f); a = fmaf(t, t, a);
                    t = fmaxf(v.w * 0.5f - tau_m, 0.0f); a = fmaf(t, t, a);
                }
            }
            a = waveReduceSum(a);
            if (lane == 0) s_red[wv] = a;
            __syncthreads();
            const float s = s_red[0] + s_red[1] + s_red[2] + s_red[3];
            __syncthreads();
            s_final = s;
            if ((s - 1.0f) * f_lo >= 0.0f) tau_lo = tau_m;
            if (fixed) break;
        }
    }

    // ---- pass 3: reread row (L3-resident) -> log(p/sum), nontemporal store ----
    // Same numeric path as the verified kernel: floor p before log (DAZ-safe),
    // bit-scrub residual inf/NaN. nt-stores keep x resident in L3 for other blocks.
    const float inv_s = 1.0f / s_final;
    for (int k = 0; k < KITER; ++k) {
        const int c = threadIdx.x + k * NT;
        if (c < CHUNKS) {
            const float4 v = xr4[c];
            f32x4 o;
            {
                const float t = fmaxf(v.x * 0.5f - tau_m, 0.0f);
                o.x = scrub_finite(__logf(fmaxf(t * t, 1e-35f) * inv_s));
            }
            {
                const float t = fmaxf(v.y * 0.5f - tau_m, 0.0f);
                o.y = scrub_finite(__logf(fmaxf(t * t, 1e-35f) * inv_s));
            }
            {
                const float t = fmaxf(v.z * 0.5f - tau_m, 0.0f);
                o.z = scrub_finite(__logf(fmaxf(t * t, 1e-35f) * inv_s));
            }
            {
                const float t = fmaxf(v.w * 0.5f - tau_m, 0.0f);
                o.w = scrub_finite(__logf(fmaxf(t * t, 1e-35f) * inv_s));
            }
            __builtin_nontemporal_store(o, reinterpret_cast<f32x4*>(orow) + c);
        }
    }
}

extern "C" void kernel_launch(void* const* d_in, const int* in_sizes, int n_in,
                              void* d_out, int out_size, void* d_ws, size_t ws_size,
                              hipStream_t stream) {
    const float* x = (const float*)d_in[0];
    float* out = (float*)d_out;
    const int rows = in_sizes[0] / D_DIM;
    entmax_log_kernel<<<dim3(rows), dim3(NT), 0, stream>>>(x, out, rows);
}

// Round 3
// 440.194 us; speedup vs baseline: 1.9377x; 1.9377x over previous
//
#include <hip/hip_runtime.h>
#include <float.h>
#include <math.h>

// Problem constants (reference: x shape (2,1024,32000) fp32, dim=-1, alpha=1.5)
#define D_DIM   32000
#define NT      256                         // 4 waves -> 8 blocks/CU
#define CHUNKS  (D_DIM / 4)                 // 8000 float4 chunks per row
#define KITER   ((CHUNKS + NT - 1) / NT)    // 32 strided iterations per thread
#define NWAVES  (NT / 64)                   // 4
#define CAPL    18                          // candidate slots per lane
#define SEG     (64 * CAPL)                 // floats per wave segment (1152)

typedef float f32x4 __attribute__((ext_vector_type(4)));

__device__ __forceinline__ float waveReduceSum(float v) {
#pragma unroll
    for (int m = 32; m >= 1; m >>= 1) v += __shfl_xor(v, m, 64);
    return v;
}

__device__ __forceinline__ float waveReduceMax(float v) {
#pragma unroll
    for (int m = 32; m >= 1; m >>= 1) v = fmaxf(v, __shfl_xor(v, m, 64));
    return v;
}

// Bit-level finite scrub: maps NaN and +/-inf to -FLT_MAX. Integer-domain so
// -ffinite-math-only cannot fold it away.
__device__ __forceinline__ float scrub_finite(float v) {
    const unsigned u = __float_as_uint(v);
    if ((u & 0x7f800000u) == 0x7f800000u) return -FLT_MAX;
    return v;
}

// Lane-local eviction: drop column entries <= thr. Entries <= runM-1 with
// runM <= final max contribute exactly 0 to every f(tau) evaluated at
// tau >= max-1, so eviction never changes any later sum. Deterministic,
// exec-masked, rare (mean live count ~3 of CAPL=18 slots).
__device__ __forceinline__ int compact_col(float* __restrict__ seg, int lane, float thr) {
    int m = 0;
#pragma unroll
    for (int i = 0; i < CAPL; ++i) {
        const float v = seg[i * 64 + lane];
        if (v > thr) { seg[m * 64 + lane] = v; ++m; }   // m <= i: in-place safe
    }
#pragma unroll
    for (int i = 0; i < CAPL; ++i)
        if (i >= m) seg[i * 64 + lane] = -FLT_MAX;      // clear stale tail
    return m;
}

__global__ __launch_bounds__(NT, 8)
void entmax_log_kernel(const float* __restrict__ x, float* __restrict__ out, int rows)
{
    const int row = blockIdx.x;
    if (row >= rows) return;
    const size_t base = (size_t)row * D_DIM;
    const float4* __restrict__ xr4 = reinterpret_cast<const float4*>(x + base);
    float* __restrict__ orow = out + base;

    // Per-wave candidate segments, layout [slot][lane] within each segment:
    // writes (lane-private columns) and strided scans are both bank-conflict-free.
    __shared__ __align__(16) float s_act[NWAVES * SEG];   // 18 KB
    __shared__ float s_red[NWAVES];
    __shared__ int   s_flag;

    const int lane = threadIdx.x & 63;
    const int wv   = threadIdx.x >> 6;
    float* __restrict__ seg = s_act + wv * SEG;

    // ---- init pads (so bisection can scan fixed CAPL slots; pads give t=0) ----
    {
        f32x4* sa4 = reinterpret_cast<f32x4*>(s_act);
#pragma unroll 2
        for (int i = threadIdx.x; i < (NWAVES * SEG) / 4; i += NT)
            sa4[i] = (f32x4){-FLT_MAX, -FLT_MAX, -FLT_MAX, -FLT_MAX};
        if (threadIdx.x == 0) s_flag = 0;
    }
    __syncthreads();

    // ---- pass 1: stream row; wave running max + single-pass candidate compaction ----
    // Admission threshold runM-1 (runM = wave running max incl. current chunk):
    // {z > runM-1} is a SUPERSET of the active set {z > max-1}; extras give 0.
    // R2 lesson: cumulative admissions have mean ~12 (sigma ~3.3) because the
    // early threshold is low -> CAPL=18 overflowed on ~every row and the
    // streaming fallback (25x re-reads, 2.8 GB fetch) ran. Fix: when a column
    // is short on space, evict dead entries (<= current thr) lane-locally.
    float runM = -FLT_MAX;
    int n = 0;
    int ovf = 0;
    for (int k = 0; k < KITER; ++k) {
        const int c = threadIdx.x + k * NT;
        float z0, z1, z2, z3;
        if (c < CHUNKS) {
            const float4 v = xr4[c];
            z0 = v.x * 0.5f; z1 = v.y * 0.5f; z2 = v.z * 0.5f; z3 = v.w * 0.5f;
        } else {
            z0 = z1 = z2 = z3 = -FLT_MAX;
        }
        float cm = fmaxf(fmaxf(z0, z1), fmaxf(z2, z3));
        cm = waveReduceMax(cm);
        runM = fmaxf(runM, cm);
        const float thr = runM - 1.0f;
        const int adm = (z0 > thr) + (z1 > thr) + (z2 > thr) + (z3 > thr);
        if (adm) {
            if (n + adm > CAPL) n = compact_col(seg, lane, thr);
            if (n + adm > CAPL) {
                ovf = 1;                       // ~1e-11 per column: adversarial-only
            } else {
                if (z0 > thr) { seg[n * 64 + lane] = z0; ++n; }
                if (z1 > thr) { seg[n * 64 + lane] = z1; ++n; }
                if (z2 > thr) { seg[n * 64 + lane] = z2; ++n; }
                if (z3 > thr) { seg[n * 64 + lane] = z3; ++n; }
            }
        }
    }
    if (ovf) s_flag = 1;   // benign race: any thread may set

    if (lane == 0) s_red[wv] = runM;     // runM is wave-uniform after reduce
    __syncthreads();
    const float max_val = fmaxf(fmaxf(s_red[0], s_red[1]), fmaxf(s_red[2], s_red[3]));
    const int flag = s_flag;
    __syncthreads();                     // s_red is reused below

    float tau_lo = max_val - 1.0f;                          // gp(1) = 1
    const float tau_hi = max_val - 0.005590169943749474f;   // (1/32000)^0.5
    float tau_m, s_final;

    if (!flag) {
        // ---- 4-wave bisection: each wave scans its own padded segment ----
        float fl = 0.0f;
#pragma unroll
        for (int k = 0; k < CAPL; ++k) {
            const float t = fmaxf(seg[k * 64 + lane] - tau_lo, 0.0f);
            fl = fmaf(t, t, fl);
        }
        fl = waveReduceSum(fl);
        if (lane == 0) s_red[wv] = fl;
        __syncthreads();
        const float f_lo = (s_red[0] + s_red[1] + s_red[2] + s_red[3]) - 1.0f;
        __syncthreads();

        float dm = tau_hi - tau_lo;
        tau_m = tau_lo;
        s_final = 1.0f;
        for (int it = 0; it < 100; ++it) {
            dm *= 0.5f;
            tau_m = tau_lo + dm;
            const bool fixed = (tau_m == tau_lo);   // uniform across block
            float a = 0.0f;
#pragma unroll
            for (int k = 0; k < CAPL; ++k) {
                const float t = fmaxf(seg[k * 64 + lane] - tau_m, 0.0f);
                a = fmaf(t, t, a);
            }
            a = waveReduceSum(a);
            if (lane == 0) s_red[wv] = a;
            __syncthreads();
            const float s = s_red[0] + s_red[1] + s_red[2] + s_red[3];
            __syncthreads();
            s_final = s;
            if ((s - 1.0f) * f_lo >= 0.0f) tau_lo = tau_m;
            if (fixed) break;
        }
    } else {
        // ---- fallback (adversarial-data only): stream row per iteration ----
        float acc = 0.0f;
        for (int k = 0; k < KITER; ++k) {
            const int c = threadIdx.x + k * NT;
            if (c < CHUNKS) {
                const float4 v = xr4[c];
                float t;
                t = fmaxf(v.x * 0.5f - tau_lo, 0.0f); acc = fmaf(t, t, acc);
                t = fmaxf(v.y * 0.5f - tau_lo, 0.0f); acc = fmaf(t, t, acc);
                t = fmaxf(v.z * 0.5f - tau_lo, 0.0f); acc = fmaf(t, t, acc);
                t = fmaxf(v.w * 0.5f - tau_lo, 0.0f); acc = fmaf(t, t, acc);
            }
        }
        acc = waveReduceSum(acc);
        if (lane == 0) s_red[wv] = acc;
        __syncthreads();
        const float f_lo = (s_red[0] + s_red[1] + s_red[2] + s_red[3]) - 1.0f;
        __syncthreads();

        float dm = tau_hi - tau_lo;
        tau_m = tau_lo;
        s_final = 1.0f;
        for (int it = 0; it < 100; ++it) {
            dm *= 0.5f;
            tau_m = tau_lo + dm;
            const bool fixed = (tau_m == tau_lo);
            float a = 0.0f;
            for (int k = 0; k < KITER; ++k) {
                const int c = threadIdx.x + k * NT;
                if (c < CHUNKS) {
                    const float4 v = xr4[c];
                    float t;
                    t = fmaxf(v.x * 0.5f - tau_m, 0.0f); a = fmaf(t, t, a);
                    t = fmaxf(v.y * 0.5f - tau_m, 0.0f); a = fmaf(t, t, a);
                    t = fmaxf(v.z * 0.5f - tau_m, 0.0f); a = fmaf(t, t, a);
                    t = fmaxf(v.w * 0.5f - tau_m, 0.0f); a = fmaf(t, t, a);
                }
            }
            a = waveReduceSum(a);
            if (lane == 0) s_red[wv] = a;
            __syncthreads();
            const float s = s_red[0] + s_red[1] + s_red[2] + s_red[3];
            __syncthreads();
            s_final = s;
            if ((s - 1.0f) * f_lo >= 0.0f) tau_lo = tau_m;
            if (fixed) break;
        }
    }

    // ---- pass 3: reread row (L3-resident) -> log(p/sum), nontemporal store ----
    // Same numeric path as the verified kernel: floor p before log (DAZ-safe),
    // bit-scrub residual inf/NaN. nt-stores keep x resident in L3 for other blocks.
    const float inv_s = 1.0f / s_final;
    for (int k = 0; k < KITER; ++k) {
        const int c = threadIdx.x + k * NT;
        if (c < CHUNKS) {
            const float4 v = xr4[c];
            f32x4 o;
            {
                const float t = fmaxf(v.x * 0.5f - tau_m, 0.0f);
                o.x = scrub_finite(__logf(fmaxf(t * t, 1e-35f) * inv_s));
            }
            {
                const float t = fmaxf(v.y * 0.5f - tau_m, 0.0f);
                o.y = scrub_finite(__logf(fmaxf(t * t, 1e-35f) * inv_s));
            }
            {
                const float t = fmaxf(v.z * 0.5f - tau_m, 0.0f);
                o.z = scrub_finite(__logf(fmaxf(t * t, 1e-35f) * inv_s));
            }
            {
                const float t = fmaxf(v.w * 0.5f - tau_m, 0.0f);
                o.w = scrub_finite(__logf(fmaxf(t * t, 1e-35f) * inv_s));
            }
            __builtin_nontemporal_store(o, reinterpret_cast<f32x4*>(orow) + c);
        }
    }
}

extern "C" void kernel_launch(void* const* d_in, const int* in_sizes, int n_in,
                              void* d_out, int out_size, void* d_ws, size_t ws_size,
                              hipStream_t stream) {
    const float* x = (const float*)d_in[0];
    float* out = (float*)d_out;
    const int rows = in_sizes[0] / D_DIM;
    entmax_log_kernel<<<dim3(rows), dim3(NT), 0, stream>>>(x, out, rows);
}